// Round 1
// baseline (581.016 us; speedup 1.0000x reference)
//
#include <hip/hip_runtime.h>
#include <hip/hip_bf16.h>
#include <stdint.h>

typedef __attribute__((ext_vector_type(8))) short short8;
typedef __attribute__((ext_vector_type(16))) float floatx16;
typedef unsigned short u16;

#define IN_DIM  1024
#define OUT_DIM 1024
#define NG      11            // spline bases per channel
#define GK      12            // + silu slot
#define KDIM    (IN_DIM * GK) // 12288
#define TOKENS  8192
#define MT      64            // M tiles (8192/128)
#define BK      96            // fused path: 8 channels x 12 slots
#define PB      104           // fused path padded LDS row stride
#define NOPS    26            // fused path B DMA ops/iter
#define GBK     64            // precomputed-A GEMM: K per iter (4 k-steps of 16)

__device__ __forceinline__ u16 f2bf(float f) {
  uint32_t u = __float_as_uint(f);
  uint32_t r = (u + 0x7fffu + ((u >> 16) & 1u)) >> 16;  // RNE
  return (u16)r;
}

// ---------------- pack Wt: bf16 [OUT_DIM][KDIM] (unchanged, verified)
__global__ __launch_bounds__(256) void pack_wt_kernel(
    const float* __restrict__ coeff, const float* __restrict__ sb,
    const float* __restrict__ ss_p, u16* __restrict__ Wt)
{
  __shared__ float cf[256 * NG];
  __shared__ __align__(16) u16 st[256 * GK];
  const int tid = threadIdx.x;
  const int b   = blockIdx.x;
  const int o   = b >> 2;
  const int i0  = (b & 3) * 256;
  const float* cbase = coeff + (size_t)o * (IN_DIM * NG) + (size_t)i0 * NG;
#pragma unroll
  for (int p = 0; p < NG; ++p) cf[p * 256 + tid] = cbase[p * 256 + tid];
  const float ss  = ss_p[0];
  const float sbv = sb[(size_t)o * IN_DIM + i0 + tid];
  __syncthreads();
  const float* cp = cf + tid * NG;
  u16 h[GK];
#pragma unroll
  for (int g = 0; g < NG; ++g) h[g] = f2bf(cp[g] * ss);
  h[NG] = f2bf(sbv);
  uint64_t V0 = (uint64_t)h[0] | ((uint64_t)h[1] << 16) | ((uint64_t)h[2] << 32) | ((uint64_t)h[3] << 48);
  uint64_t V1 = (uint64_t)h[4] | ((uint64_t)h[5] << 16) | ((uint64_t)h[6] << 32) | ((uint64_t)h[7] << 48);
  uint64_t V2 = (uint64_t)h[8] | ((uint64_t)h[9] << 16) | ((uint64_t)h[10] << 32) | ((uint64_t)h[11] << 48);
  uint64_t* sp = (uint64_t*)(st + tid * GK);
  sp[0] = V0; sp[1] = V1; sp[2] = V2;
  __syncthreads();
  const uint4* src = (const uint4*)st;
  uint4* dst = (uint4*)(Wt + (size_t)b * (256 * GK));
  dst[tid] = src[tid];
  if (tid < 128) dst[256 + tid] = src[256 + tid];
}

// Closed-form cubic B-spline + silu -> 3 u64 (verified, absmax 0.125)
__device__ __forceinline__ void expand_regs(float x, float g0, float inv_h,
                                            uint64_t& V0, uint64_t& V1, uint64_t& V2)
{
  float t  = (x - g0) * inv_h;
  float fc = floorf(t);
  int   c  = (int)fc;
  float u  = t - fc;
  float u2 = u * u;
  float w1 = 1.0f - u;
  float b0 = (w1 * w1 * w1) * (1.0f / 6.0f);
  float b1 = (0.5f * u - 1.0f) * u2 + (2.0f / 3.0f);
  float b2 = ((-0.5f * u + 0.5f) * u + 0.5f) * u + (1.0f / 6.0f);
  float b3 = (u2 * u) * (1.0f / 6.0f);
  float sil = x / (1.0f + __expf(-x));

  uint64_t P = (uint64_t)f2bf(b0) | ((uint64_t)f2bf(b1) << 16)
             | ((uint64_t)f2bf(b2) << 32) | ((uint64_t)f2bf(b3) << 48);
  int  k  = c - 3;
  bool cv = (c >= 0) && (c <= 13);
  int  kneg = (k < 0) ? -k : 0;
  uint64_t Pc = cv ? (P >> (16 * kneg)) : 0ull;
  uint32_t sh = (uint32_t)(16 * ((k < 0) ? 0 : k));

  V0 = (sh < 64)  ? (Pc << (sh & 63)) : 0ull;
  V1 = (sh == 0)  ? 0ull :
       (sh < 64)  ? (Pc >> ((64 - sh) & 63)) :
       (sh < 128) ? (Pc << ((sh - 64) & 63)) : 0ull;
  V2 = (sh <= 64) ? 0ull :
       (sh < 128) ? (Pc >> ((128 - sh) & 63)) :
                    (Pc << ((sh - 128) & 63));
  V2 = (V2 & 0x0000FFFFFFFFFFFFull) | ((uint64_t)f2bf(sil) << 48);
}

__device__ __forceinline__ void async16(const u16* g, u16* l) {
  __builtin_amdgcn_global_load_lds(
      (const __attribute__((address_space(1))) uint32_t*)g,
      (__attribute__((address_space(3))) uint32_t*)l,
      16, 0, 0);
}

// ---------------- NEW: expand X once -> Aexp[TOKENS][KDIM] bf16.
// One block per token row; thread handles 4 channels; LDS funnel -> fully
// coalesced uint4 row write (24576 B/row). Memory-bound: 33.5 MB read,
// 201 MB write. Kills the 8x redundant in-GEMM expansion VALU.
__global__ __launch_bounds__(256) void expand_x_kernel(
    const float* __restrict__ X, const float* __restrict__ grid,
    u16* __restrict__ Aexp)
{
  __shared__ __align__(16) uint4 st[1536];   // 24576 B = one expanded row
  const int tid = threadIdx.x;
  const int row = blockIdx.x;
  const float g0    = grid[0];
  const float inv_h = 1.0f / (grid[1] - grid[0]);

  float4 xv = *(const float4*)(X + (size_t)row * IN_DIM + tid * 4);
  uint64_t ev[12];
  expand_regs(xv.x, g0, inv_h, ev[0], ev[1], ev[2]);
  expand_regs(xv.y, g0, inv_h, ev[3], ev[4], ev[5]);
  expand_regs(xv.z, g0, inv_h, ev[6], ev[7], ev[8]);
  expand_regs(xv.w, g0, inv_h, ev[9], ev[10], ev[11]);
#pragma unroll
  for (int j = 0; j < 6; ++j) {
    uint4 w;
    w.x = (uint32_t)ev[2*j];     w.y = (uint32_t)(ev[2*j] >> 32);
    w.z = (uint32_t)ev[2*j+1];   w.w = (uint32_t)(ev[2*j+1] >> 32);
    st[tid * 6 + j] = w;
  }
  __syncthreads();
  uint4* dst = (uint4*)(Aexp + (size_t)row * KDIM);
#pragma unroll
  for (int j = 0; j < 6; ++j) dst[j * 256 + tid] = st[j * 256 + tid];
}

// ---------------- NEW: plain bf16 GEMM on precomputed Aexp (m97 2-phase structure).
// 128x128 tile, GBK=64, both tiles DMA'd by global_load_lds width-16.
// 32x32x16 MFMA 2x2/wave. Grid = split * 512; bn = bid&7 pins each output
// column panel to one XCD (B panel 3.1 MB -> L2-resident; A streams via L3).
__global__ __launch_bounds__(256, 3) void gemm_pre_kernel(
    const u16* __restrict__ A, const u16* __restrict__ Wt,
    float* __restrict__ out, float* __restrict__ part, int k_iters)
{
  __shared__ __align__(16) u16 As[128 * GBK];   // 16 KB
  __shared__ __align__(16) u16 Bs[128 * GBK];   // 16 KB

  const int tid  = threadIdx.x;
  const int lane = tid & 63;
  const int wave = tid >> 6;
  const int s    = blockIdx.x >> 9;       // 512 blocks per K-split
  const int r    = blockIdx.x & 511;
  const int bm   = r >> 3;
  const int bn   = r & 7;
  const int wm   = (wave >> 1) * 64;
  const int wn   = (wave & 1) * 64;
  const int l31  = lane & 31;
  const int g8   = lane >> 5;

  floatx16 acc[2][2];
#pragma unroll
  for (int a = 0; a < 2; ++a)
#pragma unroll
    for (int b = 0; b < 2; ++b)
#pragma unroll
      for (int rr = 0; rr < 16; ++rr) acc[a][b][rr] = 0.f;

  // staging: 128 rows x 64 elems x 2B = 16 KB per tile = 4 ops/thread;
  // op o, lane-consecutive g = o*256+tid -> LDS dest linear (wave-uniform
  // base + lane*16), global src per-lane (row = g>>3, 16B chunk = g&7).
  const size_t k0 = (size_t)s * k_iters * GBK;
  const u16* asrc[4]; const u16* bsrc[4]; u16* adst[4]; u16* bdst[4];
#pragma unroll
  for (int o = 0; o < 4; ++o) {
    int idx = o * 256 + tid;
    int rw = idx >> 3, c = idx & 7;
    asrc[o] = A  + (size_t)(bm * 128 + rw) * KDIM + k0 + c * 8;
    bsrc[o] = Wt + (size_t)(bn * 128 + rw) * KDIM + k0 + c * 8;
    adst[o] = As + idx * 8;
    bdst[o] = Bs + idx * 8;
  }

  for (int it = 0; it < k_iters; ++it) {
    __syncthreads();                       // waves done reading previous tile
#pragma unroll
    for (int o = 0; o < 4; ++o) async16(asrc[o], adst[o]);
#pragma unroll
    for (int o = 0; o < 4; ++o) async16(bsrc[o], bdst[o]);
#pragma unroll
    for (int o = 0; o < 4; ++o) { asrc[o] += GBK; bsrc[o] += GBK; }
    __syncthreads();                       // vmcnt drained -> tiles complete

#pragma unroll
    for (int t = 0; t < 4; ++t) {          // 4 k-steps of 16
      short8 af[2], bf[2];
#pragma unroll
      for (int ss2 = 0; ss2 < 2; ++ss2) {
        af[ss2] = *(const short8*)&As[(wm + ss2 * 32 + l31) * GBK + t * 16 + g8 * 8];
        bf[ss2] = *(const short8*)&Bs[(wn + ss2 * 32 + l31) * GBK + t * 16 + g8 * 8];
      }
#pragma unroll
      for (int sm = 0; sm < 2; ++sm)
#pragma unroll
        for (int sn = 0; sn < 2; ++sn)
          acc[sm][sn] = __builtin_amdgcn_mfma_f32_32x32x16_bf16(af[sm], bf[sn], acc[sm][sn], 0, 0, 0);
    }
  }

  // C/D map (m74/m101-verified): col=lane&31, row=(reg&3)+8*(reg>>2)+4*(lane>>5)
  float* op = (s == 0) ? out : (part + (size_t)(s - 1) * TOKENS * OUT_DIM);
#pragma unroll
  for (int sm = 0; sm < 2; ++sm)
#pragma unroll
    for (int sn = 0; sn < 2; ++sn) {
      const int row0 = bm * 128 + wm + sm * 32 + 4 * g8;
      const int col  = bn * 128 + wn + sn * 32 + l31;
#pragma unroll
      for (int reg = 0; reg < 16; ++reg) {
        int row = row0 + (reg & 3) + 8 * (reg >> 2);
        op[(size_t)row * OUT_DIM + col] = acc[sm][sn][reg];
      }
    }
}

// out += part0 + part1, float4-vectorized (split-K=3 combine)
__global__ __launch_bounds__(256) void reduce3_kernel(
    float* __restrict__ out, const float* __restrict__ part)
{
  size_t i = (size_t)blockIdx.x * 256 + threadIdx.x;
  float4* o = (float4*)out;
  const float4* p = (const float4*)part;
  const size_t n4 = (size_t)TOKENS * OUT_DIM / 4;
  float4 a = o[i], b = p[i], c = p[i + n4];
  a.x += b.x + c.x; a.y += b.y + c.y; a.z += b.z + c.z; a.w += b.w + c.w;
  o[i] = a;
}

// ---------------- OLD fused path (fallback when workspace too small) ----------------
__global__ __launch_bounds__(256, 3) void gemm_fused_kernel(
    const float* __restrict__ X, const float* __restrict__ grid,
    const u16* __restrict__ Wt, float* __restrict__ out, float* __restrict__ part,
    int k_iters)
{
  __shared__ __align__(16) u16 As[128 * PB];
  __shared__ __align__(16) u16 Bs[128 * PB];

  const int tid  = threadIdx.x;
  const int lane = tid & 63;
  const int wave = tid >> 6;
  const int mt8  = MT * 8;
  const int s    = blockIdx.x / mt8;
  const int r    = blockIdx.x - s * mt8;
  const int bm   = r % MT;
  const int bn   = r / MT;
  const int wm = (wave >> 1) * 64;
  const int wn = (wave & 1) * 64;

  const float g0    = grid[0];
  const float inv_h = 1.0f / (grid[1] - grid[0]);

  floatx16 acc[2][2];
#pragma unroll
  for (int a = 0; a < 2; ++a)
#pragma unroll
    for (int b = 0; b < 2; ++b)
#pragma unroll
      for (int rr = 0; rr < 16; ++rr) acc[a][b][rr] = 0.f;

  const int kb_u16 = s * k_iters * BK;
  const u16* bsrc[7];
  u16*       bdst[7];
  bool       bact[7];
#pragma unroll
  for (int j = 0; j < 7; ++j) {
    int o  = wave + 4 * j;
    bact[j] = (o < NOPS);
    int oc = bact[j] ? o : (NOPS - 1);
    int gidx  = oc * 64 + lane;
    int row   = gidx / 13;
    int chunk = gidx - row * 13;
    int c8    = (chunk == 12) ? 0 : chunk;
    bsrc[j] = Wt + (size_t)(bn * 128 + row) * KDIM + kb_u16 + c8 * 8;
    bdst[j] = Bs + oc * 512;
  }

  const int arow = tid & 127;
  const int half = tid >> 7;
  const float* xp = X + (size_t)(bm * 128 + arow) * IN_DIM + s * (k_iters * 8) + half * 4;
  uint4* awp = (uint4*)(As + arow * PB + half * 48);

  const int l31 = lane & 31;
  const int g   = lane >> 5;

  float4 xv = *(const float4*)xp;

  for (int it = 0; it < k_iters; ++it) {
    uint64_t ev[12];
    expand_regs(xv.x, g0, inv_h, ev[0], ev[1], ev[2]);
    expand_regs(xv.y, g0, inv_h, ev[3], ev[4], ev[5]);
    expand_regs(xv.z, g0, inv_h, ev[6], ev[7], ev[8]);
    expand_regs(xv.w, g0, inv_h, ev[9], ev[10], ev[11]);
    if (it + 1 < k_iters) xv = *(const float4*)(xp + (size_t)(it + 1) * 8);

    __syncthreads();

#pragma unroll
    for (int j = 0; j < 7; ++j)
      if (bact[j]) async16(bsrc[j] + (size_t)it * BK, bdst[j]);

#pragma unroll
    for (int j = 0; j < 6; ++j) {
      uint4 w;
      w.x = (uint32_t)ev[2*j];     w.y = (uint32_t)(ev[2*j] >> 32);
      w.z = (uint32_t)ev[2*j+1];   w.w = (uint32_t)(ev[2*j+1] >> 32);
      awp[j] = w;
    }

    __syncthreads();

#pragma unroll
    for (int t = 0; t < 6; ++t) {
      const int cc = 2 * t + g;
      short8 af[2], bf[2];
#pragma unroll
      for (int ss2 = 0; ss2 < 2; ++ss2) {
        af[ss2] = *(const short8*)&As[(wm + ss2 * 32 + l31) * PB + cc * 8];
        bf[ss2] = *(const short8*)&Bs[(wn + ss2 * 32 + l31) * PB + cc * 8];
      }
#pragma unroll
      for (int sm = 0; sm < 2; ++sm)
#pragma unroll
        for (int sn = 0; sn < 2; ++sn)
          acc[sm][sn] = __builtin_amdgcn_mfma_f32_32x32x16_bf16(af[sm], bf[sn], acc[sm][sn], 0, 0, 0);
    }
  }
  __syncthreads();

  float* op = (s == 0) ? out : part;
#pragma unroll
  for (int sm = 0; sm < 2; ++sm)
#pragma unroll
    for (int sn = 0; sn < 2; ++sn) {
      const int row0 = bm * 128 + wm + sm * 32 + 4 * g;
      const int col  = bn * 128 + wn + sn * 32 + l31;
#pragma unroll
      for (int reg = 0; reg < 16; ++reg) {
        int row = row0 + (reg & 3) + 8 * (reg >> 2);
        op[(size_t)row * OUT_DIM + col] = acc[sm][sn][reg];
      }
    }
}

__global__ __launch_bounds__(256) void reduce_kernel(
    float* __restrict__ out, const float* __restrict__ part)
{
  size_t i = (size_t)blockIdx.x * 256 + threadIdx.x;
  float4* o = (float4*)out;
  const float4* p = (const float4*)part;
  float4 a = o[i], b = p[i];
  a.x += b.x; a.y += b.y; a.z += b.z; a.w += b.w;
  o[i] = a;
}

extern "C" void kernel_launch(void* const* d_in, const int* in_sizes, int n_in,
                              void* d_out, int out_size, void* d_ws, size_t ws_size,
                              hipStream_t stream) {
  const float* x     = (const float*)d_in[0];
  const float* grid  = (const float*)d_in[1];
  const float* coeff = (const float*)d_in[2];
  const float* sb    = (const float*)d_in[3];
  const float* ss    = (const float*)d_in[4];
  float* out = (float*)d_out;

  u16* Wt = (u16*)d_ws;
  const size_t wt_bytes   = (size_t)OUT_DIM * KDIM * 2;     // 25.2 MB
  const size_t aexp_bytes = (size_t)TOKENS * KDIM * 2;      // 201.3 MB
  const size_t part_bytes = (size_t)TOKENS * OUT_DIM * 4;   // 33.6 MB

  pack_wt_kernel<<<(OUT_DIM * IN_DIM) / 256, 256, 0, stream>>>(coeff, sb, ss, Wt);

  if (ws_size >= wt_bytes + aexp_bytes + 2 * part_bytes) {
    // precompute Aexp, split-K=3: 1536 blocks = 3 blocks/CU in 2 balanced rounds
    u16*   Aexp = (u16*)((char*)d_ws + wt_bytes);
    float* part = (float*)((char*)d_ws + wt_bytes + aexp_bytes);
    expand_x_kernel<<<TOKENS, 256, 0, stream>>>(x, grid, Aexp);
    gemm_pre_kernel<<<512 * 3, 256, 0, stream>>>(Aexp, Wt, out, part, 64);
    reduce3_kernel<<<(TOKENS * OUT_DIM / 4) / 256, 256, 0, stream>>>(out, part);
  } else if (ws_size >= wt_bytes + aexp_bytes) {
    // precompute Aexp, no split (s==0 -> direct out), 512 blocks full-K
    u16* Aexp = (u16*)((char*)d_ws + wt_bytes);
    expand_x_kernel<<<TOKENS, 256, 0, stream>>>(x, grid, Aexp);
    gemm_pre_kernel<<<512, 256, 0, stream>>>(Aexp, Wt, out, nullptr, 192);
  } else if (ws_size >= wt_bytes + part_bytes) {
    // old fused split-K=2
    float* part = (float*)((char*)d_ws + wt_bytes);
    gemm_fused_kernel<<<MT * 8 * 2, 256, 0, stream>>>(x, grid, Wt, out, part, 64);
    reduce_kernel<<<(TOKENS * OUT_DIM / 4) / 256, 256, 0, stream>>>(out, part);
  } else {
    gemm_fused_kernel<<<MT * 8, 256, 0, stream>>>(x, grid, Wt, out, nullptr, 128);
  }
}

// Round 2
// 422.365 us; speedup vs baseline: 1.3756x; 1.3756x over previous
//
#include <hip/hip_runtime.h>
#include <hip/hip_bf16.h>
#include <stdint.h>

typedef __attribute__((ext_vector_type(8))) short short8;
typedef __attribute__((ext_vector_type(16))) float floatx16;
typedef unsigned short u16;

#define IN_DIM  1024
#define OUT_DIM 1024
#define NG      11            // spline bases per channel
#define GK      12            // + silu slot
#define KDIM    (IN_DIM * GK) // 12288
#define TOKENS  8192
#define MT      64            // M tiles (8192/128)
#define BK      96            // fused path: 8 channels x 12 slots
#define PB      104           // fused path padded LDS row stride
#define NOPS    26            // fused path B DMA ops/iter
#define GBK     64            // precomputed-A GEMM: K per iter (4 k-steps of 16)
#define GR      9             // LDS granules per row: 8 data + 1 pad (odd -> bank rotation)
#define GOPS    18            // 128*9/64 DMA wave-ops per tile

__device__ __forceinline__ u16 f2bf(float f) {
  uint32_t u = __float_as_uint(f);
  uint32_t r = (u + 0x7fffu + ((u >> 16) & 1u)) >> 16;  // RNE
  return (u16)r;
}

// ---------------- pack Wt: bf16 [OUT_DIM][KDIM] (unchanged, verified)
__global__ __launch_bounds__(256) void pack_wt_kernel(
    const float* __restrict__ coeff, const float* __restrict__ sb,
    const float* __restrict__ ss_p, u16* __restrict__ Wt)
{
  __shared__ float cf[256 * NG];
  __shared__ __align__(16) u16 st[256 * GK];
  const int tid = threadIdx.x;
  const int b   = blockIdx.x;
  const int o   = b >> 2;
  const int i0  = (b & 3) * 256;
  const float* cbase = coeff + (size_t)o * (IN_DIM * NG) + (size_t)i0 * NG;
#pragma unroll
  for (int p = 0; p < NG; ++p) cf[p * 256 + tid] = cbase[p * 256 + tid];
  const float ss  = ss_p[0];
  const float sbv = sb[(size_t)o * IN_DIM + i0 + tid];
  __syncthreads();
  const float* cp = cf + tid * NG;
  u16 h[GK];
#pragma unroll
  for (int g = 0; g < NG; ++g) h[g] = f2bf(cp[g] * ss);
  h[NG] = f2bf(sbv);
  uint64_t V0 = (uint64_t)h[0] | ((uint64_t)h[1] << 16) | ((uint64_t)h[2] << 32) | ((uint64_t)h[3] << 48);
  uint64_t V1 = (uint64_t)h[4] | ((uint64_t)h[5] << 16) | ((uint64_t)h[6] << 32) | ((uint64_t)h[7] << 48);
  uint64_t V2 = (uint64_t)h[8] | ((uint64_t)h[9] << 16) | ((uint64_t)h[10] << 32) | ((uint64_t)h[11] << 48);
  uint64_t* sp = (uint64_t*)(st + tid * GK);
  sp[0] = V0; sp[1] = V1; sp[2] = V2;
  __syncthreads();
  const uint4* src = (const uint4*)st;
  uint4* dst = (uint4*)(Wt + (size_t)b * (256 * GK));
  dst[tid] = src[tid];
  if (tid < 128) dst[256 + tid] = src[256 + tid];
}

// Closed-form cubic B-spline + silu -> 3 u64 (verified, absmax 0.125)
__device__ __forceinline__ void expand_regs(float x, float g0, float inv_h,
                                            uint64_t& V0, uint64_t& V1, uint64_t& V2)
{
  float t  = (x - g0) * inv_h;
  float fc = floorf(t);
  int   c  = (int)fc;
  float u  = t - fc;
  float u2 = u * u;
  float w1 = 1.0f - u;
  float b0 = (w1 * w1 * w1) * (1.0f / 6.0f);
  float b1 = (0.5f * u - 1.0f) * u2 + (2.0f / 3.0f);
  float b2 = ((-0.5f * u + 0.5f) * u + 0.5f) * u + (1.0f / 6.0f);
  float b3 = (u2 * u) * (1.0f / 6.0f);
  float sil = x / (1.0f + __expf(-x));

  uint64_t P = (uint64_t)f2bf(b0) | ((uint64_t)f2bf(b1) << 16)
             | ((uint64_t)f2bf(b2) << 32) | ((uint64_t)f2bf(b3) << 48);
  int  k  = c - 3;
  bool cv = (c >= 0) && (c <= 13);
  int  kneg = (k < 0) ? -k : 0;
  uint64_t Pc = cv ? (P >> (16 * kneg)) : 0ull;
  uint32_t sh = (uint32_t)(16 * ((k < 0) ? 0 : k));

  V0 = (sh < 64)  ? (Pc << (sh & 63)) : 0ull;
  V1 = (sh == 0)  ? 0ull :
       (sh < 64)  ? (Pc >> ((64 - sh) & 63)) :
       (sh < 128) ? (Pc << ((sh - 64) & 63)) : 0ull;
  V2 = (sh <= 64) ? 0ull :
       (sh < 128) ? (Pc >> ((128 - sh) & 63)) :
                    (Pc << ((sh - 128) & 63));
  V2 = (V2 & 0x0000FFFFFFFFFFFFull) | ((uint64_t)f2bf(sil) << 48);
}

__device__ __forceinline__ void async16(const u16* g, u16* l) {
  __builtin_amdgcn_global_load_lds(
      (const __attribute__((address_space(1))) uint32_t*)g,
      (__attribute__((address_space(3))) uint32_t*)l,
      16, 0, 0);
}

// ---------------- expand X once -> Aexp[TOKENS][KDIM] bf16 (memory-bound, ~50us)
__global__ __launch_bounds__(256) void expand_x_kernel(
    const float* __restrict__ X, const float* __restrict__ grid,
    u16* __restrict__ Aexp)
{
  __shared__ __align__(16) uint4 st[1536];   // 24576 B = one expanded row
  const int tid = threadIdx.x;
  const int row = blockIdx.x;
  const float g0    = grid[0];
  const float inv_h = 1.0f / (grid[1] - grid[0]);

  float4 xv = *(const float4*)(X + (size_t)row * IN_DIM + tid * 4);
  uint64_t ev[12];
  expand_regs(xv.x, g0, inv_h, ev[0], ev[1], ev[2]);
  expand_regs(xv.y, g0, inv_h, ev[3], ev[4], ev[5]);
  expand_regs(xv.z, g0, inv_h, ev[6], ev[7], ev[8]);
  expand_regs(xv.w, g0, inv_h, ev[9], ev[10], ev[11]);
#pragma unroll
  for (int j = 0; j < 6; ++j) {
    uint4 w;
    w.x = (uint32_t)ev[2*j];     w.y = (uint32_t)(ev[2*j] >> 32);
    w.z = (uint32_t)ev[2*j+1];   w.w = (uint32_t)(ev[2*j+1] >> 32);
    st[tid * 6 + j] = w;
  }
  __syncthreads();
  uint4* dst = (uint4*)(Aexp + (size_t)row * KDIM);
#pragma unroll
  for (int j = 0; j < 6; ++j) dst[j * 256 + tid] = st[j * 256 + tid];
}

// ---------------- plain bf16 GEMM on precomputed Aexp, v2.
// 128x128 tile, GBK=64. LDS rows = 9 granules (8 data + 1 pad-dup): stride
// 144B = 36 dw -> (36*row)%32 = 4*(row%8) rotates 32 consecutive rows over
// all 8 bank groups -> 4 lanes/group = min service -> ~0 ds_read conflicts
// (same mechanism as the fused kernel's 13-granule layout, measured 0).
// Block map: bm = r&63, bn = r>>6 -> bid%8 = bm%8, so the 8 bn-blocks
// sharing an A strip co-run on ONE XCD (A fetched once per strip).
// Split-K=2 -> 1024 blocks, LDS 36.9KB -> 4 blocks/CU, exactly resident.
__global__ __launch_bounds__(256, 4) void gemm_pre_kernel(
    const u16* __restrict__ A, const u16* __restrict__ Wt,
    float* __restrict__ out, float* __restrict__ part, int k_iters)
{
  __shared__ __align__(16) u16 As[128 * GR * 8];   // 18432 B
  __shared__ __align__(16) u16 Bs[128 * GR * 8];   // 18432 B

  const int tid  = threadIdx.x;
  const int lane = tid & 63;
  const int wave = tid >> 6;
  const int s    = blockIdx.x >> 9;       // 512 blocks per K-split
  const int r    = blockIdx.x & 511;
  const int bm   = r & 63;
  const int bn   = r >> 6;
  const int wm   = (wave >> 1) * 64;
  const int wn   = (wave & 1) * 64;
  const int l31  = lane & 31;
  const int g8   = lane >> 5;

  floatx16 acc[2][2];
#pragma unroll
  for (int a = 0; a < 2; ++a)
#pragma unroll
    for (int b = 0; b < 2; ++b)
#pragma unroll
      for (int rr = 0; rr < 16; ++rr) acc[a][b][rr] = 0.f;

  // DMA setup: op o (= wave + 4j, o < GOPS) moves granules [64o, 64o+64).
  // lane: gidx = 64o+lane; row = gidx/9; chunk = gidx%9; chunk 8 = pad -> dup chunk 0.
  const size_t k0 = (size_t)s * k_iters * GBK;
  const u16* asrc[5]; const u16* bsrc[5]; int doff[5]; bool act[5];
#pragma unroll
  for (int j = 0; j < 5; ++j) {
    int o  = wave + 4 * j;
    act[j] = (o < GOPS);
    int oc = act[j] ? o : (GOPS - 1);
    int gidx  = oc * 64 + lane;
    int row   = gidx / 9;
    int chunk = gidx - row * 9;
    int c8    = (chunk == 8) ? 0 : chunk;
    asrc[j] = A  + (size_t)(bm * 128 + row) * KDIM + k0 + c8 * 8;
    bsrc[j] = Wt + (size_t)(bn * 128 + row) * KDIM + k0 + c8 * 8;
    doff[j] = oc * 512;   // 64 granules = 1024 B = 512 u16 per op
  }

  for (int it = 0; it < k_iters; ++it) {
    __syncthreads();                       // waves done reading previous tile
#pragma unroll
    for (int j = 0; j < 5; ++j)
      if (act[j]) async16(asrc[j] + (size_t)it * GBK, As + doff[j]);
#pragma unroll
    for (int j = 0; j < 5; ++j)
      if (act[j]) async16(bsrc[j] + (size_t)it * GBK, Bs + doff[j]);
    __syncthreads();                       // vmcnt drained -> tiles complete

#pragma unroll
    for (int t = 0; t < 4; ++t) {          // 4 k-steps of 16
      short8 af[2], bf[2];
#pragma unroll
      for (int ss2 = 0; ss2 < 2; ++ss2) {
        af[ss2] = *(const short8*)&As[(wm + ss2 * 32 + l31) * (GR * 8) + (2 * t + g8) * 8];
        bf[ss2] = *(const short8*)&Bs[(wn + ss2 * 32 + l31) * (GR * 8) + (2 * t + g8) * 8];
      }
#pragma unroll
      for (int sm = 0; sm < 2; ++sm)
#pragma unroll
        for (int sn = 0; sn < 2; ++sn)
          acc[sm][sn] = __builtin_amdgcn_mfma_f32_32x32x16_bf16(af[sm], bf[sn], acc[sm][sn], 0, 0, 0);
    }
  }

  // C/D map (m74/m101-verified): col=lane&31, row=(reg&3)+8*(reg>>2)+4*(lane>>5)
  float* op = (s == 0) ? out : part;
#pragma unroll
  for (int sm = 0; sm < 2; ++sm)
#pragma unroll
    for (int sn = 0; sn < 2; ++sn) {
      const int row0 = bm * 128 + wm + sm * 32 + 4 * g8;
      const int col  = bn * 128 + wn + sn * 32 + l31;
#pragma unroll
      for (int reg = 0; reg < 16; ++reg) {
        int row = row0 + (reg & 3) + 8 * (reg >> 2);
        op[(size_t)row * OUT_DIM + col] = acc[sm][sn][reg];
      }
    }
}

// out += part, float4-vectorized
__global__ __launch_bounds__(256) void reduce_kernel(
    float* __restrict__ out, const float* __restrict__ part)
{
  size_t i = (size_t)blockIdx.x * 256 + threadIdx.x;
  float4* o = (float4*)out;
  const float4* p = (const float4*)part;
  float4 a = o[i], b = p[i];
  a.x += b.x; a.y += b.y; a.z += b.z; a.w += b.w;
  o[i] = a;
}

// ---------------- OLD fused path (fallback when workspace too small) ----------------
__global__ __launch_bounds__(256, 3) void gemm_fused_kernel(
    const float* __restrict__ X, const float* __restrict__ grid,
    const u16* __restrict__ Wt, float* __restrict__ out, float* __restrict__ part,
    int k_iters)
{
  __shared__ __align__(16) u16 As[128 * PB];
  __shared__ __align__(16) u16 Bs[128 * PB];

  const int tid  = threadIdx.x;
  const int lane = tid & 63;
  const int wave = tid >> 6;
  const int mt8  = MT * 8;
  const int s    = blockIdx.x / mt8;
  const int r    = blockIdx.x - s * mt8;
  const int bm   = r % MT;
  const int bn   = r / MT;
  const int wm = (wave >> 1) * 64;
  const int wn = (wave & 1) * 64;

  const float g0    = grid[0];
  const float inv_h = 1.0f / (grid[1] - grid[0]);

  floatx16 acc[2][2];
#pragma unroll
  for (int a = 0; a < 2; ++a)
#pragma unroll
    for (int b = 0; b < 2; ++b)
#pragma unroll
      for (int rr = 0; rr < 16; ++rr) acc[a][b][rr] = 0.f;

  const int kb_u16 = s * k_iters * BK;
  const u16* bsrc[7];
  u16*       bdst[7];
  bool       bact[7];
#pragma unroll
  for (int j = 0; j < 7; ++j) {
    int o  = wave + 4 * j;
    bact[j] = (o < NOPS);
    int oc = bact[j] ? o : (NOPS - 1);
    int gidx  = oc * 64 + lane;
    int row   = gidx / 13;
    int chunk = gidx - row * 13;
    int c8    = (chunk == 12) ? 0 : chunk;
    bsrc[j] = Wt + (size_t)(bn * 128 + row) * KDIM + kb_u16 + c8 * 8;
    bdst[j] = Bs + oc * 512;
  }

  const int arow = tid & 127;
  const int half = tid >> 7;
  const float* xp = X + (size_t)(bm * 128 + arow) * IN_DIM + s * (k_iters * 8) + half * 4;
  uint4* awp = (uint4*)(As + arow * PB + half * 48);

  const int l31 = lane & 31;
  const int g   = lane >> 5;

  float4 xv = *(const float4*)xp;

  for (int it = 0; it < k_iters; ++it) {
    uint64_t ev[12];
    expand_regs(xv.x, g0, inv_h, ev[0], ev[1], ev[2]);
    expand_regs(xv.y, g0, inv_h, ev[3], ev[4], ev[5]);
    expand_regs(xv.z, g0, inv_h, ev[6], ev[7], ev[8]);
    expand_regs(xv.w, g0, inv_h, ev[9], ev[10], ev[11]);
    if (it + 1 < k_iters) xv = *(const float4*)(xp + (size_t)(it + 1) * 8);

    __syncthreads();

#pragma unroll
    for (int j = 0; j < 7; ++j)
      if (bact[j]) async16(bsrc[j] + (size_t)it * BK, bdst[j]);

#pragma unroll
    for (int j = 0; j < 6; ++j) {
      uint4 w;
      w.x = (uint32_t)ev[2*j];     w.y = (uint32_t)(ev[2*j] >> 32);
      w.z = (uint32_t)ev[2*j+1];   w.w = (uint32_t)(ev[2*j+1] >> 32);
      awp[j] = w;
    }

    __syncthreads();

#pragma unroll
    for (int t = 0; t < 6; ++t) {
      const int cc = 2 * t + g;
      short8 af[2], bf[2];
#pragma unroll
      for (int ss2 = 0; ss2 < 2; ++ss2) {
        af[ss2] = *(const short8*)&As[(wm + ss2 * 32 + l31) * PB + cc * 8];
        bf[ss2] = *(const short8*)&Bs[(wn + ss2 * 32 + l31) * PB + cc * 8];
      }
#pragma unroll
      for (int sm = 0; sm < 2; ++sm)
#pragma unroll
        for (int sn = 0; sn < 2; ++sn)
          acc[sm][sn] = __builtin_amdgcn_mfma_f32_32x32x16_bf16(af[sm], bf[sn], acc[sm][sn], 0, 0, 0);
    }
  }
  __syncthreads();

  float* op = (s == 0) ? out : part;
#pragma unroll
  for (int sm = 0; sm < 2; ++sm)
#pragma unroll
    for (int sn = 0; sn < 2; ++sn) {
      const int row0 = bm * 128 + wm + sm * 32 + 4 * g;
      const int col  = bn * 128 + wn + sn * 32 + l31;
#pragma unroll
      for (int reg = 0; reg < 16; ++reg) {
        int row = row0 + (reg & 3) + 8 * (reg >> 2);
        op[(size_t)row * OUT_DIM + col] = acc[sm][sn][reg];
      }
    }
}

extern "C" void kernel_launch(void* const* d_in, const int* in_sizes, int n_in,
                              void* d_out, int out_size, void* d_ws, size_t ws_size,
                              hipStream_t stream) {
  const float* x     = (const float*)d_in[0];
  const float* grid  = (const float*)d_in[1];
  const float* coeff = (const float*)d_in[2];
  const float* sb    = (const float*)d_in[3];
  const float* ss    = (const float*)d_in[4];
  float* out = (float*)d_out;

  u16* Wt = (u16*)d_ws;
  const size_t wt_bytes   = (size_t)OUT_DIM * KDIM * 2;     // 25.2 MB
  const size_t aexp_bytes = (size_t)TOKENS * KDIM * 2;      // 201.3 MB
  const size_t part_bytes = (size_t)TOKENS * OUT_DIM * 4;   // 33.6 MB

  pack_wt_kernel<<<(OUT_DIM * IN_DIM) / 256, 256, 0, stream>>>(coeff, sb, ss, Wt);

  if (ws_size >= wt_bytes + aexp_bytes + part_bytes) {
    // precompute Aexp, split-K=2: 1024 blocks = 4 blocks/CU, exactly resident
    u16*   Aexp = (u16*)((char*)d_ws + wt_bytes);
    float* part = (float*)((char*)d_ws + wt_bytes + aexp_bytes);
    expand_x_kernel<<<TOKENS, 256, 0, stream>>>(x, grid, Aexp);
    gemm_pre_kernel<<<512 * 2, 256, 0, stream>>>(Aexp, Wt, out, part, 96);
    reduce_kernel<<<(TOKENS * OUT_DIM / 4) / 256, 256, 0, stream>>>(out, part);
  } else if (ws_size >= wt_bytes + aexp_bytes) {
    // precompute Aexp, no split (s==0 -> direct out), 512 blocks full-K
    u16* Aexp = (u16*)((char*)d_ws + wt_bytes);
    expand_x_kernel<<<TOKENS, 256, 0, stream>>>(x, grid, Aexp);
    gemm_pre_kernel<<<512, 256, 0, stream>>>(Aexp, Wt, out, nullptr, 192);
  } else if (ws_size >= wt_bytes + part_bytes) {
    // old fused split-K=2
    float* part = (float*)((char*)d_ws + wt_bytes);
    gemm_fused_kernel<<<MT * 8 * 2, 256, 0, stream>>>(x, grid, Wt, out, part, 64);
    reduce_kernel<<<(TOKENS * OUT_DIM / 4) / 256, 256, 0, stream>>>(out, part);
  } else {
    gemm_fused_kernel<<<MT * 8, 256, 0, stream>>>(x, grid, Wt, out, nullptr, 128);
  }
}